// Round 1
// baseline (828.040 us; speedup 1.0000x reference)
//
#include <hip/hip_runtime.h>
#include <math.h>

#define N_NODES 100000
#define N_EDGES 1200000
#define DIM 64
#define TDIM 32
#define NLAYERS 3
#define NGRAPH 500
#define NP (N_NODES + 1)
#define NB_SCAN ((NP + 255) / 256)   // 391

// ---------------- setup kernels ----------------

__global__ __launch_bounds__(512) void k_graph_start(const int* __restrict__ gid,
                                                     int* __restrict__ gstart,
                                                     float* __restrict__ inv_safe) {
    int t = threadIdx.x;
    if (t <= NGRAPH) {
        int lo = 0, hi = N_NODES;
        while (lo < hi) {
            int mid = (lo + hi) >> 1;
            if (gid[mid] < t) lo = mid + 1; else hi = mid;
        }
        gstart[t] = lo;
    }
    __syncthreads();
    if (t < NGRAPH) {
        int c = gstart[t + 1] - gstart[t];
        inv_safe[t] = 1.0f / (float)(c > 1 ? c : 1);
    }
}

__global__ __launch_bounds__(256) void k_hist(const int* __restrict__ dst, int* __restrict__ deg) {
    int e = blockIdx.x * 256 + threadIdx.x;
    if (e < N_EDGES) atomicAdd(&deg[dst[e]], 1);
}

__global__ __launch_bounds__(256) void k_scanA(const int* __restrict__ deg, int* __restrict__ bsum) {
    __shared__ int s[256];
    int t = threadIdx.x;
    int i = blockIdx.x * 256 + t;
    s[t] = (i < NP) ? deg[i] : 0;
    __syncthreads();
    for (int off = 128; off > 0; off >>= 1) {
        if (t < off) s[t] += s[t + off];
        __syncthreads();
    }
    if (t == 0) bsum[blockIdx.x] = s[0];
}

__global__ __launch_bounds__(512) void k_scanB(const int* __restrict__ bsum, int* __restrict__ boff) {
    __shared__ int s[512];
    int t = threadIdx.x;
    s[t] = (t < NB_SCAN) ? bsum[t] : 0;
    __syncthreads();
    for (int off = 1; off < 512; off <<= 1) {
        int v = (t >= off) ? s[t - off] : 0;
        __syncthreads();
        s[t] += v;
        __syncthreads();
    }
    if (t < NB_SCAN) boff[t] = t ? s[t - 1] : 0;
}

__global__ __launch_bounds__(256) void k_scanC(const int* __restrict__ deg, const int* __restrict__ boff,
                                               int* __restrict__ offs) {
    __shared__ int s[256];
    int t = threadIdx.x;
    int i = blockIdx.x * 256 + t;
    int v = (i < NP) ? deg[i] : 0;
    s[t] = v;
    __syncthreads();
    for (int off = 1; off < 256; off <<= 1) {
        int u = (t >= off) ? s[t - off] : 0;
        __syncthreads();
        s[t] += u;
        __syncthreads();
    }
    if (i < NP) offs[i] = boff[blockIdx.x] + s[t] - v;  // exclusive scan
}

__global__ __launch_bounds__(256) void k_cursor(const int* __restrict__ offs, int* __restrict__ cur) {
    int i = blockIdx.x * 256 + threadIdx.x;
    if (i < N_NODES) cur[i] = offs[i];
}

__global__ __launch_bounds__(256) void k_fill(const int* __restrict__ src, const int* __restrict__ dst,
                                              int* __restrict__ cur, int* __restrict__ csr) {
    int e = blockIdx.x * 256 + threadIdx.x;
    if (e < N_EDGES) {
        int d = dst[e];
        int p = atomicAdd(&cur[d], 1);
        csr[p] = src[e];
    }
}

// ---------------- per-layer: aggregation (GINConv input) ----------------
// hin[n] = (1+eps)*feat[n] + sum_{e: dst==n} feat[src[e]]
__global__ __launch_bounds__(256) void k_agg(const float* __restrict__ feat, const int* __restrict__ offs,
                                             const int* __restrict__ csr, const float* __restrict__ eps,
                                             int l, float* __restrict__ hin) {
    int w = threadIdx.x >> 6;
    int lane = threadIdx.x & 63;
    int node = blockIdx.x * 4 + w;
    if (node >= N_NODES) return;
    int e0 = offs[node], e1 = offs[node + 1];
    float acc = 0.f;
    // 4-wide manual unroll to keep multiple gathers in flight
    for (int e = e0; e < e1; e += 4) {
        int eL = e1 - 1;
        int i1 = (e + 1 < eL) ? e + 1 : eL;
        int i2 = (e + 2 < eL) ? e + 2 : eL;
        int i3 = (e + 3 < eL) ? e + 3 : eL;
        int s0 = csr[e], s1 = csr[i1], s2 = csr[i2], s3 = csr[i3];
        float v0 = feat[s0 * DIM + lane];
        float v1 = (e + 1 <= eL) ? feat[s1 * DIM + lane] : 0.f;
        float v2 = (e + 2 <= eL) ? feat[s2 * DIM + lane] : 0.f;
        float v3 = (e + 3 <= eL) ? feat[s3 * DIM + lane] : 0.f;
        acc += (v0 + v1) + (v2 + v3);
    }
    float ep = 1.0f + eps[l];
    hin[node * DIM + lane] = ep * feat[node * DIM + lane] + acc;
}

// ---------------- per-layer: conv MLP  h = relu(hin@W1+b1)@W2+b2 ----------------
__global__ __launch_bounds__(256) void k_mlp(const float* __restrict__ hin,
                                             const float* __restrict__ w1, const float* __restrict__ b1,
                                             const float* __restrict__ w2, const float* __restrict__ b2,
                                             float* __restrict__ hout) {
    __shared__ __align__(16) float sW1[64 * 64];
    __shared__ __align__(16) float sW2[64 * 64];
    __shared__ __align__(16) float sIn[64 * 68];
    __shared__ __align__(16) float sT[64 * 68];
    __shared__ float sB1[64], sB2[64];
    int t = threadIdx.x;
    int row0 = blockIdx.x * 64;
#pragma unroll
    for (int i = 0; i < 16; i++) {
        sW1[i * 256 + t] = w1[i * 256 + t];
        sW2[i * 256 + t] = w2[i * 256 + t];
    }
    if (t < 64) { sB1[t] = b1[t]; sB2[t] = b2[t]; }
#pragma unroll
    for (int i = 0; i < 16; i++) {
        int idx = i * 256 + t;
        int r = idx >> 6, c = idx & 63;
        int row = row0 + r;
        sIn[r * 68 + c] = (row < N_NODES) ? hin[row * 64 + c] : 0.f;
    }
    __syncthreads();

    int c0 = (t & 15) * 4;
    int r0 = (t >> 4) * 4;
    float acc[4][4];
#pragma unroll
    for (int i = 0; i < 4; i++)
#pragma unroll
        for (int j = 0; j < 4; j++) acc[i][j] = sB1[c0 + j];
#pragma unroll 4
    for (int k = 0; k < 64; k++) {
        float4 w = *(const float4*)&sW1[k * 64 + c0];
#pragma unroll
        for (int i = 0; i < 4; i++) {
            float a = sIn[(r0 + i) * 68 + k];
            acc[i][0] += a * w.x; acc[i][1] += a * w.y;
            acc[i][2] += a * w.z; acc[i][3] += a * w.w;
        }
    }
#pragma unroll
    for (int i = 0; i < 4; i++)
#pragma unroll
        for (int j = 0; j < 4; j++)
            sT[(r0 + i) * 68 + c0 + j] = fmaxf(acc[i][j], 0.f);
    __syncthreads();

    float acc2[4][4];
#pragma unroll
    for (int i = 0; i < 4; i++)
#pragma unroll
        for (int j = 0; j < 4; j++) acc2[i][j] = sB2[c0 + j];
#pragma unroll 4
    for (int k = 0; k < 64; k++) {
        float4 w = *(const float4*)&sW2[k * 64 + c0];
#pragma unroll
        for (int i = 0; i < 4; i++) {
            float a = sT[(r0 + i) * 68 + k];
            acc2[i][0] += a * w.x; acc2[i][1] += a * w.y;
            acc2[i][2] += a * w.z; acc2[i][3] += a * w.w;
        }
    }
#pragma unroll
    for (int i = 0; i < 4; i++) {
        int row = row0 + r0 + i;
        if (row < N_NODES) {
            float4 o; o.x = acc2[i][0]; o.y = acc2[i][1]; o.z = acc2[i][2]; o.w = acc2[i][3];
            *(float4*)&hout[row * 64 + c0] = o;
        }
    }
}

// ---------------- per-layer: GraphNorm + relu + projection MLP + mean-pool ----------------
// one block per graph (graph_ids sorted -> contiguous ranges)
__global__ __launch_bounds__(256) void k_norm_proj(const float* __restrict__ h,
                                                   const int* __restrict__ gstart,
                                                   const float* __restrict__ inv_safe,
                                                   const float* __restrict__ gnw, const float* __restrict__ gnb,
                                                   const float* __restrict__ gns,
                                                   const float* __restrict__ p1, const float* __restrict__ pb1,
                                                   const float* __restrict__ p2, const float* __restrict__ pb2,
                                                   float* __restrict__ feat, float* __restrict__ out, int l) {
    __shared__ __align__(16) float sP1[64 * 64];
    __shared__ __align__(16) float sP2[64 * 32];
    __shared__ float sPB1[64], sPB2[32];
    __shared__ __align__(16) float sFeat[32 * 68];
    __shared__ __align__(16) float sM[32 * 72];
    __shared__ float sRed[4][64];
    __shared__ float sMeanScale[64], sCoef[64], sGnB[64];
    __shared__ float sZ[32 * 33];

    int t = threadIdx.x;
    int g = blockIdx.x;
    int s = gstart[g], epos = gstart[g + 1];
    int nn = epos - s;
    float inv = inv_safe[g];

#pragma unroll
    for (int i = 0; i < 16; i++) sP1[i * 256 + t] = p1[i * 256 + t];
#pragma unroll
    for (int i = 0; i < 8; i++) sP2[i * 256 + t] = p2[i * 256 + t];
    if (t < 64) sPB1[t] = pb1[t];
    if (t < 32) sPB2[t] = pb2[t];

    int lane = t & 63, wy = t >> 6;

    // pass 1: mean
    float p = 0.f;
    for (int i = s + wy; i < epos; i += 4) p += h[i * 64 + lane];
    sRed[wy][lane] = p;
    __syncthreads();
    if (t < 64) {
        float m = (sRed[0][t] + sRed[1][t] + sRed[2][t] + sRed[3][t]) * inv;
        sMeanScale[t] = m * gns[t];
        sGnB[t] = gnb[t];
    }
    __syncthreads();

    // pass 2: var of (h - mean*scale)
    float ms = sMeanScale[lane];
    p = 0.f;
    for (int i = s + wy; i < epos; i += 4) {
        float sub = h[i * 64 + lane] - ms;
        p += sub * sub;
    }
    sRed[wy][lane] = p;
    __syncthreads();
    if (t < 64) {
        float v = (sRed[0][t] + sRed[1][t] + sRed[2][t] + sRed[3][t]) * inv;
        sCoef[t] = gnw[t] * rsqrtf(v + 1e-8f);
    }
    __syncthreads();

    // pass 3: apply norm + relu, write feat for next layer
    float coef = sCoef[lane], gb = sGnB[lane];
    for (int i = s + wy; i < epos; i += 4) {
        float sub = h[i * 64 + lane] - ms;
        feat[i * 64 + lane] = fmaxf(coef * sub + gb, 0.f);
    }

    // projection MLP + pooling (recompute feat from h to avoid global RW hazard)
    float zacc[4] = {0.f, 0.f, 0.f, 0.f};
    int ntiles = (nn + 31) >> 5;
    int rr = t >> 3;             // GEMM2 row (0..31)
    int cz0 = (t & 7) * 4;       // GEMM2 cols
    int c0 = (t & 15) * 4;       // GEMM1 cols
    int r0 = (t >> 4) * 2;       // GEMM1 rows (2 per thread)

    for (int tile = 0; tile < ntiles; tile++) {
        int base = s + tile * 32;
        __syncthreads();  // protect sFeat/sM reuse
#pragma unroll
        for (int i = 0; i < 8; i++) {
            int idx = i * 256 + t;
            int r = idx >> 6, c = idx & 63;
            int node = base + r;
            float val = 0.f;
            if (node < epos)
                val = fmaxf(sCoef[c] * (h[node * 64 + c] - sMeanScale[c]) + sGnB[c], 0.f);
            sFeat[r * 68 + c] = val;
        }
        __syncthreads();
        // GEMM1: t_mid = relu(sFeat @ P1 + pb1)
        float a0[4], a1[4];
#pragma unroll
        for (int j = 0; j < 4; j++) { a0[j] = sPB1[c0 + j]; a1[j] = sPB1[c0 + j]; }
#pragma unroll 4
        for (int k = 0; k < 64; k++) {
            float4 w = *(const float4*)&sP1[k * 64 + c0];
            float x0 = sFeat[r0 * 68 + k];
            float x1 = sFeat[(r0 + 1) * 68 + k];
            a0[0] += x0 * w.x; a0[1] += x0 * w.y; a0[2] += x0 * w.z; a0[3] += x0 * w.w;
            a1[0] += x1 * w.x; a1[1] += x1 * w.y; a1[2] += x1 * w.z; a1[3] += x1 * w.w;
        }
#pragma unroll
        for (int j = 0; j < 4; j++) {
            sM[r0 * 72 + c0 + j] = fmaxf(a0[j], 0.f);
            sM[(r0 + 1) * 72 + c0 + j] = fmaxf(a1[j], 0.f);
        }
        __syncthreads();
        // GEMM2: z = t_mid @ P2 (+pb2 added at the end), accumulate pooled sum
        if (base + rr < epos) {
#pragma unroll 4
            for (int k = 0; k < 64; k++) {
                float4 w = *(const float4*)&sP2[k * 32 + cz0];
                float x = sM[rr * 72 + k];
                zacc[0] += x * w.x; zacc[1] += x * w.y; zacc[2] += x * w.z; zacc[3] += x * w.w;
            }
        }
    }
    __syncthreads();
#pragma unroll
    for (int j = 0; j < 4; j++) sZ[rr * 33 + cz0 + j] = zacc[j];
    __syncthreads();
    if (t < 32) {
        float sum = 0.f;
        for (int r = 0; r < 32; r++) sum += sZ[r * 33 + t];
        out[g * (NLAYERS * TDIM) + l * TDIM + t] = (nn > 0) ? (sum * inv + sPB2[t]) : 0.f;
    }
}

// ---------------- launcher ----------------

extern "C" void kernel_launch(void* const* d_in, const int* in_sizes, int n_in,
                              void* d_out, int out_size, void* d_ws, size_t ws_size,
                              hipStream_t stream) {
    const float* x        = (const float*)d_in[0];
    const int*   src      = (const int*)d_in[1];
    const int*   dst      = (const int*)d_in[2];
    const int*   gid      = (const int*)d_in[3];
    const float* eps      = (const float*)d_in[4];
    const float* conv_w1  = (const float*)d_in[5];
    const float* conv_b1  = (const float*)d_in[6];
    const float* conv_w2  = (const float*)d_in[7];
    const float* conv_b2  = (const float*)d_in[8];
    const float* gn_w     = (const float*)d_in[9];
    const float* gn_b     = (const float*)d_in[10];
    const float* gn_s     = (const float*)d_in[11];
    const float* proj_w1  = (const float*)d_in[12];
    const float* proj_b1  = (const float*)d_in[13];
    const float* proj_w2  = (const float*)d_in[14];
    const float* proj_b2  = (const float*)d_in[15];
    float* out = (float*)d_out;

    char* ws = (char*)d_ws;
    size_t off = 0;
    auto alloc = [&](size_t bytes) { char* p = ws + off; off += (bytes + 255) & ~(size_t)255; return p; };
    int*   offs     = (int*)alloc(NP * sizeof(int));
    int*   deg      = (int*)alloc(NP * sizeof(int));      // also reused as cursor
    int*   gstart   = (int*)alloc((NGRAPH + 1) * sizeof(int));
    float* inv_safe = (float*)alloc(NGRAPH * sizeof(float));
    int*   bsum     = (int*)alloc(NB_SCAN * sizeof(int));
    int*   boff     = (int*)alloc(NB_SCAN * sizeof(int));
    int*   csr      = (int*)alloc(N_EDGES * sizeof(int));
    float* hin      = (float*)alloc((size_t)N_NODES * DIM * sizeof(float));
    float* hbuf     = (float*)alloc((size_t)N_NODES * DIM * sizeof(float));
    float* featbuf  = (float*)alloc((size_t)N_NODES * DIM * sizeof(float));

    // setup
    k_graph_start<<<1, 512, 0, stream>>>(gid, gstart, inv_safe);
    hipMemsetAsync(deg, 0, NP * sizeof(int), stream);
    int ebl = (N_EDGES + 255) / 256;
    k_hist<<<ebl, 256, 0, stream>>>(dst, deg);
    k_scanA<<<NB_SCAN, 256, 0, stream>>>(deg, bsum);
    k_scanB<<<1, 512, 0, stream>>>(bsum, boff);
    k_scanC<<<NB_SCAN, 256, 0, stream>>>(deg, boff, offs);
    k_cursor<<<NB_SCAN, 256, 0, stream>>>(offs, deg);   // deg becomes cursor
    k_fill<<<ebl, 256, 0, stream>>>(src, dst, deg, csr);

    int aggbl = (N_NODES + 3) / 4;
    int mlpbl = (N_NODES + 63) / 64;
    for (int l = 0; l < NLAYERS; l++) {
        const float* fin = (l == 0) ? x : featbuf;
        k_agg<<<aggbl, 256, 0, stream>>>(fin, offs, csr, eps, l, hin);
        k_mlp<<<mlpbl, 256, 0, stream>>>(hin, conv_w1 + l * 4096, conv_b1 + l * 64,
                                         conv_w2 + l * 4096, conv_b2 + l * 64, hbuf);
        k_norm_proj<<<NGRAPH, 256, 0, stream>>>(hbuf, gstart, inv_safe,
                                                gn_w + l * 64, gn_b + l * 64, gn_s + l * 64,
                                                proj_w1 + l * 4096, proj_b1 + l * 64,
                                                proj_w2 + l * 2048, proj_b2 + l * 32,
                                                featbuf, out, l);
    }
}